// Round 13
// baseline (449.562 us; speedup 1.0000x reference)
//
#include <hip/hip_runtime.h>
#include <math.h>

#define BB   2
#define SS   2048
#define HIDD 2048
#define NHH  16
#define HDD  128
#define RDD  64
#define KVCC 512
#define QCC  1536
#define DQK  192
#define MROWS 4096

using bf16x8 = __attribute__((ext_vector_type(8))) short;
using short4v = __attribute__((ext_vector_type(4))) short;
using f32x4  = __attribute__((ext_vector_type(4))) float;
using f32x16 = __attribute__((ext_vector_type(16))) float;

static __device__ __forceinline__ float b2f(short s) {
    unsigned u = ((unsigned)(unsigned short)s) << 16;
    union { unsigned u; float f; } v; v.u = u; return v.f;
}
static __device__ __forceinline__ short f2b(float f) {
    union { float f; unsigned u; } v; v.f = f;
    unsigned r = (v.u + 0x7fffu + ((v.u >> 16) & 1u)) >> 16;
    return (short)r;
}
static __device__ __forceinline__ unsigned cvtpk(float lo, float hi) {
    unsigned r;
    asm("v_cvt_pk_bf16_f32 %0, %1, %2" : "=v"(r) : "v"(lo), "v"(hi));
    return r;
}

#define GLOAD16(gsrc, ldst) \
    __builtin_amdgcn_global_load_lds((const __attribute__((address_space(1))) void*)(gsrc), \
                                     (__attribute__((address_space(3))) void*)(ldst), 16, 0, 0)

// ---------------- fp32 -> bf16 convert ----------------
__global__ void cvt_kernel(const float* __restrict__ in, short* __restrict__ out) {
    int i = (blockIdx.x * blockDim.x + threadIdx.x) * 4;
    float4 v = *(const float4*)(in + i);
    short4v o;
    o[0] = f2b(v.x); o[1] = f2b(v.y); o[2] = f2b(v.z); o[3] = f2b(v.w);
    *(short4v*)(out + i) = o;
}

// ---------------- all 8 weight transposes in ONE launch ----------------
__global__ void wtrans_kernel(
    const float* __restrict__ W0, const float* __restrict__ W1,
    const float* __restrict__ W2, const float* __restrict__ W3,
    const float* __restrict__ W4, const float* __restrict__ W5,
    const float* __restrict__ W6, const float* __restrict__ W7,
    short* __restrict__ D0, short* __restrict__ D1,
    short* __restrict__ D2, short* __restrict__ D3) {
    __shared__ float t[32][33];
    int bid = blockIdx.x;
    const float* W; short* Dst; int K, N, lt;
    if (bid < 4096) {
        if (bid < 1024) { W = W0; Dst = D0;                        K = 2048; N = 512;  lt = bid; }
        else            { W = W1; Dst = D0 + (size_t)512 * 2048;   K = 2048; N = 1536; lt = bid - 1024; }
    } else if (bid < 6656) {
        if (bid < 5120)      { W = W2; Dst = D1;                       K = 512; N = 2048; lt = bid - 4096; }
        else if (bid < 6144) { W = W3; Dst = D1 + (size_t)2048 * 512;  K = 512; N = 2048; lt = bid - 5120; }
        else                 { W = W4; Dst = D1 + (size_t)4096 * 512;  K = 512; N = 1024; lt = bid - 6144; }
    } else if (bid < 11264) {
        if (bid < 9728) { W = W5; Dst = D2;                        K = 1536; N = 2048; lt = bid - 6656; }
        else            { W = W6; Dst = D2 + (size_t)2048 * 1536;  K = 1536; N = 1024; lt = bid - 9728; }
    } else { W = W7; Dst = D3; K = 2048; N = 2048; lt = bid - 11264; }
    int ntx = N >> 5;
    int n0 = (lt % ntx) * 32, k0 = (lt / ntx) * 32;
    int tx = threadIdx.x, ty = threadIdx.y;   // block(32,8)
#pragma unroll
    for (int i = 0; i < 4; i++)
        t[ty + i * 8][tx] = W[(size_t)(k0 + ty + i * 8) * N + n0 + tx];
    __syncthreads();
#pragma unroll
    for (int i = 0; i < 4; i++)
        Dst[(size_t)(n0 + ty + i * 8) * K + k0 + tx] = f2b(t[tx][ty + i * 8]);
}

// ---------------- 128x128 MFMA GEMM (m97 structure, BK=32), segment-routed epilogues ----
// ID 0: fp32 out (+b0).  ID 1: [kvc|qc] bf16.
// ID 2: [ku->kbuf | vu->vtb TRANSPOSED (bh,d,s) | kr->kbuf].  ID 3: [qu|qr]->qbuf.
template <int ID>
__global__ __launch_bounds__(256) void gemm128(
    const short* __restrict__ A, const short* __restrict__ Bt,
    const float* __restrict__ b0, const float* __restrict__ b1, const float* __restrict__ b2,
    void* __restrict__ C0, void* __restrict__ C1,
    int M, int N, int K) {
    __shared__ short Asm[4096];   // [128][32]
    __shared__ short Bsm[4096];
    int tid = threadIdx.x, lane = tid & 63, w = tid >> 6;
    int wm = w >> 1, wn = w & 1;
    int m0 = blockIdx.y * 128, n0 = blockIdx.x * 128;
    int fr = lane & 15, fk = (lane >> 4) * 8;
    const short* Ag = A + (size_t)(m0 + (tid >> 2)) * K + (tid & 3) * 8;
    const short* Bg = Bt + (size_t)(n0 + (tid >> 2)) * K + (tid & 3) * 8;
    f32x4 acc[4][4] = {};
    for (int k0 = 0; k0 < K; k0 += 32) {
        __syncthreads();
        GLOAD16(Ag + k0, &Asm[tid * 8]);
        GLOAD16(Ag + k0 + (size_t)64 * K, &Asm[2048 + tid * 8]);
        GLOAD16(Bg + k0, &Bsm[tid * 8]);
        GLOAD16(Bg + k0 + (size_t)64 * K, &Bsm[2048 + tid * 8]);
        __syncthreads();
        bf16x8 af[4], bfv[4];
#pragma unroll
        for (int m = 0; m < 4; m++)
            af[m] = *(const bf16x8*)&Asm[(wm * 64 + m * 16 + fr) * 32 + fk];
#pragma unroll
        for (int n = 0; n < 4; n++)
            bfv[n] = *(const bf16x8*)&Bsm[(wn * 64 + n * 16 + fr) * 32 + fk];
#pragma unroll
        for (int m = 0; m < 4; m++)
#pragma unroll
            for (int n = 0; n < 4; n++)
                acc[m][n] = __builtin_amdgcn_mfma_f32_16x16x32_bf16(af[m], bfv[n], acc[m][n], 0, 0, 0);
    }
#pragma unroll
    for (int m = 0; m < 4; m++)
#pragma unroll
        for (int n = 0; n < 4; n++)
#pragma unroll
            for (int r = 0; r < 4; r++) {
                int row = m0 + wm * 64 + m * 16 + ((lane >> 4) << 2) + r;
                int col = n0 + wn * 64 + n * 16 + fr;
                float v = acc[m][n][r];
                if constexpr (ID == 0) {
                    ((float*)C0)[(size_t)row * N + col] = v + b0[col];
                } else if constexpr (ID == 1) {
                    if (col < KVCC)
                        ((short*)C0)[(size_t)row * KVCC + col] = f2b(v + b0[col]);
                    else
                        ((short*)C1)[(size_t)row * QCC + (col - KVCC)] = f2b(v + b1[col - KVCC]);
                } else if constexpr (ID == 2) {
                    int b = row >> 11, s = row & (SS - 1);
                    if (col < 2048) {
                        int h = col >> 7, d = col & 127;
                        ((short*)C0)[(((size_t)(b * NHH + h)) * SS + s) * DQK + d] = f2b(v + b0[col]);
                    } else if (col < 4096) {
                        int c = col - 2048; int h = c >> 7, d = c & 127;
                        // direct transposed (bh, d, s) for attention V
                        ((short*)C1)[(((size_t)(b * NHH + h)) * HDD + d) * SS + s] = f2b(v + b1[c]);
                    } else {
                        int c = col - 4096; int h = c >> 6, d = c & 63;
                        ((short*)C0)[(((size_t)(b * NHH + h)) * SS + s) * DQK + HDD + d] = f2b(v + b2[c]);
                    }
                } else {
                    int b = row >> 11, s = row & (SS - 1);
                    if (col < 2048) {
                        int h = col >> 7, d = col & 127;
                        ((short*)C0)[(((size_t)(b * NHH + h)) * SS + s) * DQK + d] = f2b(v + b0[col]);
                    } else {
                        int c = col - 2048; int h = c >> 6, d = c & 63;
                        ((short*)C0)[(((size_t)(b * NHH + h)) * SS + s) * DQK + HDD + d] = f2b(v + b1[c]);
                    }
                }
            }
}

// ---------------- RoPE on [*, *, 128..191] of (B*NH, S, 192), both K and Q ----------------
__global__ void rope_kernel(short* __restrict__ Tk, short* __restrict__ Tq) {
    int idx = blockIdx.x * blockDim.x + threadIdx.x;
    const int HALF = BB * NHH * SS * 32;
    short* T = (idx < HALF) ? Tk : Tq;
    int id = (idx < HALF) ? idx : idx - HALF;
    int i = id & 31;
    int s = (id >> 5) & (SS - 1);
    int bh = id >> 16;
    short* p = T + ((size_t)bh * SS + s) * DQK + HDD;
    float t1 = b2f(p[i]), t2 = b2f(p[i + 32]);
    float inv = exp2f(-(float)i * 0.41524101186092034f);   // 10000^(-i/32)
    float ang = (float)s * inv;
    float sn, cs;
    sincosf(ang, &sn, &cs);
    p[i] = f2b(t1 * cs - t2 * sn);
    p[i + 32] = f2b(t2 * cs + t1 * sn);
}

// ---------------- causal flash attention: key-split balanced schedule ----------------
// 512 blocks = 32 bh x 16 slots. slot = (pa, role): pair (lo=pa, hi=15-pa), c = 15-2*pa.
// role A: lo full (ctx) + hi keys [0, c) -> partial 0.  role B: hi keys [c, end) -> partial 1.
// Every block = exactly 17 serial key-tiles. Partials merged by merge_kernel.
__global__ __launch_bounds__(256, 2) void attn_kernel(
    const short* __restrict__ Q, const short* __restrict__ Kg,
    const short* __restrict__ Vt, short* __restrict__ ctx,
    float* __restrict__ Opart, float* __restrict__ Ml) {
    __shared__ short Ksm[2][64 * 192];    // 2 x 24KB, swizzled linear
    __shared__ short Vsm[2][128 * 64];    // 2 x 16KB, V^T (d,k), swizzled
    int tid = threadIdx.x, lane = tid & 63, w = tid >> 6;
    int hf = lane >> 5, l31 = lane & 31;
    int bid = blockIdx.x;
    int bh = bid & 31, slot = bid >> 5;
    int pa = slot & 7, role = slot >> 3;
    int lo = pa, hi = 15 - pa;
    int c = 15 - 2 * pa;
    int bb = bh >> 4, hd = bh & 15;
    const short* Qp = Q + (size_t)bh * SS * DQK;
    const short* Kp = Kg + (size_t)bh * SS * DQK;
    const char*  Vp = (const char*)(Vt + (size_t)bh * HDD * SS);
    const float scale = 0.07216878364870323f;   // 1/sqrt(192)
    const float L2E = 1.44269504088896f;

    auto stageK = [&](int key0, int b) {
#pragma unroll
        for (int pp = 0; pp < 6; pp++) {
            int flat = pp * 4096 + tid * 16;          // byte offset in 64x384B tile
            int row = flat / 384, bir = flat - row * 384;
            const char* src = (const char*)Kp + (size_t)(key0 + row) * 384 + (bir ^ ((row & 7) << 4));
            GLOAD16(src, (char*)Ksm[b] + flat);
        }
    };
    auto stageV = [&](int key0, int b) {
#pragma unroll
        for (int cc = 0; cc < 4; cc++) {
            int flat = cc * 4096 + tid * 16;           // byte offset in 128x128B tile
            int d = flat >> 7, bik = flat & 127;
            const char* src = Vp + (size_t)d * (SS * 2) + (size_t)key0 * 2 + (bik ^ ((d & 7) << 4));
            GLOAD16(src, (char*)Vsm[b] + flat);
        }
    };

    int nseg = (role == 0) ? 2 : 1;
    for (int sg = 0; sg < nseg; sg++) {
        int qt_, kb, ke, mode;
        if (role == 0) {
            if (sg == 0) { qt_ = lo; kb = 0; ke = 2 * lo + 2; mode = 0; }
            else         { qt_ = hi; kb = 0; ke = c;          mode = 1; }
        } else          { qt_ = hi; kb = c; ke = 2 * hi + 2;  mode = 2; }
        int q0 = qt_ * 128;
        int wr0 = q0 + w * 32;
        int qrow = wr0 + l31;
        // Q as B-operand fragments: B[k=8*hf+j][col=l31], dims 16s+8hf+j
        bf16x8 qf[12];
#pragma unroll
        for (int s = 0; s < 12; s++)
            qf[s] = *(const bf16x8*)(Qp + (size_t)qrow * DQK + s * 16 + hf * 8);
        f32x16 acc[4] = {};
        float mrow = -1e30f, lsum = 0.f;

        stageK(kb * 64, 0); stageV(kb * 64, 0);
        __syncthreads();

        for (int t = kb; t < ke; t++) {
            int key0 = t * 64;
            int cur = (t - kb) & 1;
            if (t + 1 < ke) { stageK(key0 + 64, cur ^ 1); stageV(key0 + 64, cur ^ 1); }
            bool active = (key0 <= wr0 + 31);
            if (active) {
                // ---- swapped QK^T: D[key][qrow] ----
                f32x16 z = {};
                f32x16 sv0 = z, sv1 = z;
                int xr = (l31 & 7) << 4;
                const char* Kb = (const char*)Ksm[cur];
                __builtin_amdgcn_s_setprio(1);
#pragma unroll
                for (int s = 0; s < 12; s++) {
                    bf16x8 k0 = *(const bf16x8*)(Kb + l31 * 384 + ((s * 32 + hf * 16) ^ xr));
                    bf16x8 k1 = *(const bf16x8*)(Kb + (32 + l31) * 384 + ((s * 32 + hf * 16) ^ xr));
                    sv0 = __builtin_amdgcn_mfma_f32_32x32x16_bf16(k0, qf[s], sv0, 0, 0, 0);
                    sv1 = __builtin_amdgcn_mfma_f32_32x32x16_bf16(k1, qf[s], sv1, 0, 0, 0);
                }
                __builtin_amdgcn_s_setprio(0);
                // ---- mask (raw scores; scale folded into exp) ----
                bool domask = (key0 + 63 > wr0);
                float p[32];
#pragma unroll
                for (int t2 = 0; t2 < 2; t2++)
#pragma unroll
                    for (int r = 0; r < 16; r++) {
                        float v = (t2 ? sv1[r] : sv0[r]);
                        int key = key0 + 32 * t2 + (r & 3) + 8 * (r >> 2) + 4 * hf;
                        if (domask && key > qrow) v = -1e30f;
                        p[t2 * 16 + r] = v;
                    }
                // ---- tree max ----
                float tm[16];
#pragma unroll
                for (int i = 0; i < 16; i++) tm[i] = fmaxf(p[i], p[i + 16]);
#pragma unroll
                for (int i = 0; i < 8; i++) tm[i] = fmaxf(tm[i], tm[i + 8]);
#pragma unroll
                for (int i = 0; i < 4; i++) tm[i] = fmaxf(tm[i], tm[i + 4]);
                float pmaxs = fmaxf(fmaxf(tm[0], tm[1]), fmaxf(tm[2], tm[3])) * scale;
                // ---- defer-max rescale ----
                if (__any(pmaxs > mrow + 8.f)) {
                    float pc = fmaxf(pmaxs, __shfl_xor(pmaxs, 32, 64));
                    float mn = fmaxf(mrow, pc);
                    float al = exp2f((mrow - mn) * L2E);
                    mrow = mn;
                    lsum *= al;
                    float arl[16];
#pragma unroll
                    for (int r = 0; r < 16; r++)
                        arl[r] = __shfl(al, (r & 3) + 8 * (r >> 2) + 4 * hf, 64);
#pragma unroll
                    for (int n = 0; n < 4; n++)
#pragma unroll
                        for (int r = 0; r < 16; r++)
                            acc[n][r] *= arl[r];
                }
                // ---- exp with folded scale ----
                float sL = scale * L2E, mL = mrow * L2E;
#pragma unroll
                for (int i = 0; i < 32; i++)
                    p[i] = exp2f(fmaf(p[i], sL, -mL));
                // ---- tree sum ----
                float ts[16];
#pragma unroll
                for (int i = 0; i < 16; i++) ts[i] = p[i] + p[i + 16];
#pragma unroll
                for (int i = 0; i < 8; i++) ts[i] = ts[i] + ts[i + 8];
#pragma unroll
                for (int i = 0; i < 4; i++) ts[i] = ts[i] + ts[i + 4];
                lsum += (ts[0] + ts[1]) + (ts[2] + ts[3]);
                // ---- pack P to bf16 + exchange halves ----
                bf16x8 afv[4];
#pragma unroll
                for (int g = 0; g < 4; g++) {
                    int base = (g >> 1) * 16 + (g & 1) * 8;
                    unsigned a01 = cvtpk(p[base + 0], p[base + 1]);
                    unsigned a23 = cvtpk(p[base + 2], p[base + 3]);
                    unsigned b01 = cvtpk(p[base + 4], p[base + 5]);
                    unsigned b23 = cvtpk(p[base + 6], p[base + 7]);
                    unsigned s0 = hf ? a01 : b01, s1 = hf ? a23 : b23;
                    unsigned r0 = (unsigned)__shfl_xor((int)s0, 32, 64);
                    unsigned r1 = (unsigned)__shfl_xor((int)s1, 32, 64);
                    union { unsigned u[4]; bf16x8 v; } af;
                    af.u[0] = hf ? r0 : a01;
                    af.u[1] = hf ? r1 : a23;
                    af.u[2] = hf ? b01 : r0;
                    af.u[3] = hf ? b23 : r1;
                    afv[g] = af.v;
                }
                // ---- PV ----
                const char* Vb = (const char*)Vsm[cur];
                __builtin_amdgcn_s_setprio(1);
#pragma unroll
                for (int g = 0; g < 4; g++)
#pragma unroll
                    for (int n = 0; n < 4; n++) {
                        int d = n * 32 + l31;
                        bf16x8 vf = *(const bf16x8*)(Vb + d * 128 + ((g * 32 + hf * 16) ^ ((d & 7) << 4)));
                        acc[n] = __builtin_amdgcn_mfma_f32_32x32x16_bf16(afv[g], vf, acc[n], 0, 0, 0);
                    }
                __builtin_amdgcn_s_setprio(0);
            }
            __syncthreads();
        }
        // ---- segment epilogue ----
        lsum += __shfl_xor(lsum, 32, 64);
        if (mode == 0) {
            float rc = 1.0f / lsum;
            float rcl[16];
#pragma unroll
            for (int r = 0; r < 16; r++)
                rcl[r] = __shfl(rc, (r & 3) + 8 * (r >> 2) + 4 * hf, 64);
#pragma unroll
            for (int n = 0; n < 4; n++)
#pragma unroll
                for (int r = 0; r < 16; r++) {
                    int row = wr0 + (r & 3) + 8 * (r >> 2) + 4 * hf;
                    int d = n * 32 + l31;
                    ctx[((size_t)(bb * SS + row)) * (NHH * HDD) + hd * HDD + d] = f2b(acc[n][r] * rcl[r]);
                }
        } else {
            int si = bh * 8 + pa;
            float* Op = Opart + ((size_t)si * 2 + (mode - 1)) * 16384;
            float* mlp = Ml + ((size_t)si * 2 + (mode - 1)) * 256;
#pragma unroll
            for (int n = 0; n < 4; n++)
#pragma unroll
                for (int r = 0; r < 16; r++) {
                    int row = w * 32 + (r & 3) + 8 * (r >> 2) + 4 * hf;
                    Op[row * 128 + n * 32 + l31] = acc[n][r];
                }
            if (hf == 0) {
                int row = w * 32 + l31;
                mlp[row * 2] = mrow;
                mlp[row * 2 + 1] = lsum;
            }
        }
    }
}

// ---------------- merge split-attention partials -> ctx ----------------
__global__ __launch_bounds__(256) void merge_kernel(
    const float* __restrict__ Opart, const float* __restrict__ Ml,
    short* __restrict__ ctx) {
    int si = blockIdx.x;
    int bh = si >> 3, pa = si & 7;
    int hi = 15 - pa;
    int q0 = hi * 128;
    int bb = bh >> 4, hd = bh & 15;
    const float* Oa = Opart + (size_t)si * 2 * 16384;
    const float* Ob = Oa + 16384;
    const float* mla = Ml + (size_t)si * 2 * 256;
    const float* mlb = mla + 256;
    int tid = threadIdx.x;
    int rr = tid >> 5, dq = (tid & 31) * 4;
    const float L2E = 1.44269504088896f;
#pragma unroll
    for (int it = 0; it < 16; it++) {
        int row = it * 8 + rr;
        float mA = mla[row * 2], lA = mla[row * 2 + 1];
        float mB = mlb[row * 2], lB = mlb[row * 2 + 1];
        float M = fmaxf(mA, mB);
        float wA = exp2f((mA - M) * L2E), wB = exp2f((mB - M) * L2E);
        float rc = 1.0f / (lA * wA + lB * wB);
        float4 oa = *(const float4*)(Oa + row * 128 + dq);
        float4 ob = *(const float4*)(Ob + row * 128 + dq);
        size_t o = ((size_t)(bb * SS + q0 + row)) * (NHH * HDD) + hd * HDD + dq;
        short4v r;
        r[0] = f2b((oa.x * wA + ob.x * wB) * rc);
        r[1] = f2b((oa.y * wA + ob.y * wB) * rc);
        r[2] = f2b((oa.z * wA + ob.z * wB) * rc);
        r[3] = f2b((oa.w * wA + ob.w * wB) * rc);
        *(short4v*)(ctx + o) = r;
    }
}

extern "C" void kernel_launch(void* const* d_in, const int* in_sizes, int n_in,
                              void* d_out, int out_size, void* d_ws, size_t ws_size,
                              hipStream_t stream) {
    const float* x     = (const float*)d_in[0];
    const float* W_kvd = (const float*)d_in[1];  const float* b_kvd = (const float*)d_in[2];
    const float* W_ku  = (const float*)d_in[3];  const float* b_ku  = (const float*)d_in[4];
    const float* W_vu  = (const float*)d_in[5];  const float* b_vu  = (const float*)d_in[6];
    const float* W_kr  = (const float*)d_in[7];  const float* b_kr  = (const float*)d_in[8];
    const float* W_qd  = (const float*)d_in[9];  const float* b_qd  = (const float*)d_in[10];
    const float* W_qu  = (const float*)d_in[11]; const float* b_qu  = (const float*)d_in[12];
    const float* W_qr  = (const float*)d_in[13]; const float* b_qr  = (const float*)d_in[14];
    const float* W_o   = (const float*)d_in[15]; const float* b_o   = (const float*)d_in[16];
    float* out = (float*)d_out;

    char* p = (char*)d_ws;
    auto alloc = [&](size_t elems) {
        short* r = (short*)p;
        p += ((elems * 2) + 255) & ~(size_t)255;
        return r;
    };
    short* xb   = alloc((size_t)MROWS * HIDD);
    short* kvc  = alloc((size_t)MROWS * KVCC);
    short* qc   = alloc((size_t)MROWS * QCC);
    short* kbuf = alloc((size_t)BB * NHH * SS * DQK);
    short* qbuf = alloc((size_t)BB * NHH * SS * DQK);
    short* vtb  = alloc((size_t)BB * NHH * HDD * SS);
    short* ctx  = alloc((size_t)MROWS * NHH * HDD);
    short* Wt1  = alloc((size_t)2048 * 2048);
    short* Wt2  = alloc((size_t)5120 * 512);
    short* Wt3  = alloc((size_t)3072 * 1536);
    short* Wt4  = alloc((size_t)2048 * 2048);

    // attention split partials reuse buffers dead by attn time:
    //   Opart: 256 tiles x 2 parts x 16384 f32 = 33,554,432 B == xb+kvc+qc exactly
    //   Ml:    256 x 2 x 256 f32 = 512 KB, placed in Wt1 (dead after gemm1)
    float* Opart = (float*)xb;
    float* Ml    = (float*)Wt1;

    cvt_kernel<<<dim3((MROWS * HIDD) / 1024), dim3(256), 0, stream>>>(x, xb);
    dim3 tb(32, 8);
    wtrans_kernel<<<dim3(15360), tb, 0, stream>>>(
        W_kvd, W_qd, W_ku, W_vu, W_kr, W_qu, W_qr, W_o, Wt1, Wt2, Wt3, Wt4);

    gemm128<1><<<dim3(2048 / 128, MROWS / 128), 256, 0, stream>>>(
        xb, Wt1, b_kvd, b_qd, nullptr, kvc, qc, MROWS, 2048, 2048);
    gemm128<2><<<dim3(5120 / 128, MROWS / 128), 256, 0, stream>>>(
        kvc, Wt2, b_ku, b_vu, b_kr, kbuf, vtb, MROWS, 5120, 512);
    gemm128<3><<<dim3(3072 / 128, MROWS / 128), 256, 0, stream>>>(
        qc, Wt3, b_qu, b_qr, nullptr, qbuf, nullptr, MROWS, 3072, 1536);

    rope_kernel<<<dim3((2 * BB * NHH * SS * 32) / 256), dim3(256), 0, stream>>>(kbuf, qbuf);

    attn_kernel<<<dim3(512), 256, 0, stream>>>(qbuf, kbuf, vtb, ctx, Opart, Ml);
    merge_kernel<<<dim3(256), 256, 0, stream>>>(Opart, Ml, ctx);

    gemm128<0><<<dim3(HIDD / 128, MROWS / 128), 256, 0, stream>>>(
        ctx, Wt4, b_o, nullptr, nullptr, out, nullptr, MROWS, HIDD, NHH * HDD);
}

// Round 14
// 394.757 us; speedup vs baseline: 1.1388x; 1.1388x over previous
//
#include <hip/hip_runtime.h>
#include <math.h>

#define BB   2
#define SS   2048
#define HIDD 2048
#define NHH  16
#define HDD  128
#define RDD  64
#define KVCC 512
#define QCC  1536
#define DQK  192
#define MROWS 4096

using bf16x8 = __attribute__((ext_vector_type(8))) short;
using short4v = __attribute__((ext_vector_type(4))) short;
using f32x4  = __attribute__((ext_vector_type(4))) float;
using f32x16 = __attribute__((ext_vector_type(16))) float;

static __device__ __forceinline__ float b2f(short s) {
    unsigned u = ((unsigned)(unsigned short)s) << 16;
    union { unsigned u; float f; } v; v.u = u; return v.f;
}
static __device__ __forceinline__ short f2b(float f) {
    union { float f; unsigned u; } v; v.f = f;
    unsigned r = (v.u + 0x7fffu + ((v.u >> 16) & 1u)) >> 16;
    return (short)r;
}
static __device__ __forceinline__ unsigned cvtpk(float lo, float hi) {
    unsigned r;
    asm("v_cvt_pk_bf16_f32 %0, %1, %2" : "=v"(r) : "v"(lo), "v"(hi));
    return r;
}

#define GLOAD16(gsrc, ldst) \
    __builtin_amdgcn_global_load_lds((const __attribute__((address_space(1))) void*)(gsrc), \
                                     (__attribute__((address_space(3))) void*)(ldst), 16, 0, 0)

// ---------------- fp32 -> bf16 convert ----------------
__global__ void cvt_kernel(const float* __restrict__ in, short* __restrict__ out) {
    int i = (blockIdx.x * blockDim.x + threadIdx.x) * 4;
    float4 v = *(const float4*)(in + i);
    short4v o;
    o[0] = f2b(v.x); o[1] = f2b(v.y); o[2] = f2b(v.z); o[3] = f2b(v.w);
    *(short4v*)(out + i) = o;
}

// ---------------- all 8 weight transposes in ONE launch ----------------
__global__ void wtrans_kernel(
    const float* __restrict__ W0, const float* __restrict__ W1,
    const float* __restrict__ W2, const float* __restrict__ W3,
    const float* __restrict__ W4, const float* __restrict__ W5,
    const float* __restrict__ W6, const float* __restrict__ W7,
    short* __restrict__ D0, short* __restrict__ D1,
    short* __restrict__ D2, short* __restrict__ D3) {
    __shared__ float t[32][33];
    int bid = blockIdx.x;
    const float* W; short* Dst; int K, N, lt;
    if (bid < 4096) {
        if (bid < 1024) { W = W0; Dst = D0;                        K = 2048; N = 512;  lt = bid; }
        else            { W = W1; Dst = D0 + (size_t)512 * 2048;   K = 2048; N = 1536; lt = bid - 1024; }
    } else if (bid < 6656) {
        if (bid < 5120)      { W = W2; Dst = D1;                       K = 512; N = 2048; lt = bid - 4096; }
        else if (bid < 6144) { W = W3; Dst = D1 + (size_t)2048 * 512;  K = 512; N = 2048; lt = bid - 5120; }
        else                 { W = W4; Dst = D1 + (size_t)4096 * 512;  K = 512; N = 1024; lt = bid - 6144; }
    } else if (bid < 11264) {
        if (bid < 9728) { W = W5; Dst = D2;                        K = 1536; N = 2048; lt = bid - 6656; }
        else            { W = W6; Dst = D2 + (size_t)2048 * 1536;  K = 1536; N = 1024; lt = bid - 9728; }
    } else { W = W7; Dst = D3; K = 2048; N = 2048; lt = bid - 11264; }
    int ntx = N >> 5;
    int n0 = (lt % ntx) * 32, k0 = (lt / ntx) * 32;
    int tx = threadIdx.x, ty = threadIdx.y;   // block(32,8)
#pragma unroll
    for (int i = 0; i < 4; i++)
        t[ty + i * 8][tx] = W[(size_t)(k0 + ty + i * 8) * N + n0 + tx];
    __syncthreads();
#pragma unroll
    for (int i = 0; i < 4; i++)
        Dst[(size_t)(n0 + ty + i * 8) * K + k0 + tx] = f2b(t[tx][ty + i * 8]);
}

// ---------------- 128x128 MFMA GEMM, T3 2-phase: dbuf LDS + 1 barrier/iter ----------
// ID 0: fp32 out (+b0).  ID 1: [kvc|qc] bf16.
// ID 2: [ku->kbuf | vu->vtb TRANSPOSED (bh,d,s) | kr->kbuf].  ID 3: [qu|qr]->qbuf.
template <int ID>
__global__ __launch_bounds__(256) void gemm128(
    const short* __restrict__ A, const short* __restrict__ Bt,
    const float* __restrict__ b0, const float* __restrict__ b1, const float* __restrict__ b2,
    void* __restrict__ C0, void* __restrict__ C1,
    int M, int N, int K) {
    __shared__ short Asm[2][4096];   // 2 x [128][32]
    __shared__ short Bsm[2][4096];
    int tid = threadIdx.x, lane = tid & 63, w = tid >> 6;
    int wm = w >> 1, wn = w & 1;
    int m0 = blockIdx.y * 128, n0 = blockIdx.x * 128;
    int fr = lane & 15, fk = (lane >> 4) * 8;
    const short* Ag = A + (size_t)(m0 + (tid >> 2)) * K + (tid & 3) * 8;
    const short* Bg = Bt + (size_t)(n0 + (tid >> 2)) * K + (tid & 3) * 8;
    auto stage = [&](int k0, int b) {
        GLOAD16(Ag + k0, &Asm[b][tid * 8]);
        GLOAD16(Ag + k0 + (size_t)64 * K, &Asm[b][2048 + tid * 8]);
        GLOAD16(Bg + k0, &Bsm[b][tid * 8]);
        GLOAD16(Bg + k0 + (size_t)64 * K, &Bsm[b][2048 + tid * 8]);
    };
    f32x4 acc[4][4] = {};
    stage(0, 0);
    __syncthreads();   // buf0 ready
    int cur = 0;
    for (int k0 = 0; k0 < K; k0 += 32) {
        if (k0 + 32 < K) stage(k0 + 32, cur ^ 1);   // prefetch next K-tile
        bf16x8 af[4], bfv[4];
#pragma unroll
        for (int m = 0; m < 4; m++)
            af[m] = *(const bf16x8*)&Asm[cur][(wm * 64 + m * 16 + fr) * 32 + fk];
#pragma unroll
        for (int n = 0; n < 4; n++)
            bfv[n] = *(const bf16x8*)&Bsm[cur][(wn * 64 + n * 16 + fr) * 32 + fk];
#pragma unroll
        for (int m = 0; m < 4; m++)
#pragma unroll
            for (int n = 0; n < 4; n++)
                acc[m][n] = __builtin_amdgcn_mfma_f32_16x16x32_bf16(af[m], bfv[n], acc[m][n], 0, 0, 0);
        __syncthreads();   // drains prefetch (issued a full compute-phase ago) + read sync
        cur ^= 1;
    }
#pragma unroll
    for (int m = 0; m < 4; m++)
#pragma unroll
        for (int n = 0; n < 4; n++)
#pragma unroll
            for (int r = 0; r < 4; r++) {
                int row = m0 + wm * 64 + m * 16 + ((lane >> 4) << 2) + r;
                int col = n0 + wn * 64 + n * 16 + fr;
                float v = acc[m][n][r];
                if constexpr (ID == 0) {
                    ((float*)C0)[(size_t)row * N + col] = v + b0[col];
                } else if constexpr (ID == 1) {
                    if (col < KVCC)
                        ((short*)C0)[(size_t)row * KVCC + col] = f2b(v + b0[col]);
                    else
                        ((short*)C1)[(size_t)row * QCC + (col - KVCC)] = f2b(v + b1[col - KVCC]);
                } else if constexpr (ID == 2) {
                    int b = row >> 11, s = row & (SS - 1);
                    if (col < 2048) {
                        int h = col >> 7, d = col & 127;
                        ((short*)C0)[(((size_t)(b * NHH + h)) * SS + s) * DQK + d] = f2b(v + b0[col]);
                    } else if (col < 4096) {
                        int c = col - 2048; int h = c >> 7, d = c & 127;
                        // direct transposed (bh, d, s) for attention V
                        ((short*)C1)[(((size_t)(b * NHH + h)) * HDD + d) * SS + s] = f2b(v + b1[c]);
                    } else {
                        int c = col - 4096; int h = c >> 6, d = c & 63;
                        ((short*)C0)[(((size_t)(b * NHH + h)) * SS + s) * DQK + HDD + d] = f2b(v + b2[c]);
                    }
                } else {
                    int b = row >> 11, s = row & (SS - 1);
                    if (col < 2048) {
                        int h = col >> 7, d = col & 127;
                        ((short*)C0)[(((size_t)(b * NHH + h)) * SS + s) * DQK + d] = f2b(v + b0[col]);
                    } else {
                        int c = col - 2048; int h = c >> 6, d = c & 63;
                        ((short*)C0)[(((size_t)(b * NHH + h)) * SS + s) * DQK + HDD + d] = f2b(v + b1[c]);
                    }
                }
            }
}

// ---------------- RoPE on [*, *, 128..191] of (B*NH, S, 192), both K and Q ----------------
__global__ void rope_kernel(short* __restrict__ Tk, short* __restrict__ Tq) {
    int idx = blockIdx.x * blockDim.x + threadIdx.x;
    const int HALF = BB * NHH * SS * 32;
    short* T = (idx < HALF) ? Tk : Tq;
    int id = (idx < HALF) ? idx : idx - HALF;
    int i = id & 31;
    int s = (id >> 5) & (SS - 1);
    int bh = id >> 16;
    short* p = T + ((size_t)bh * SS + s) * DQK + HDD;
    float t1 = b2f(p[i]), t2 = b2f(p[i + 32]);
    float inv = exp2f(-(float)i * 0.41524101186092034f);   // 10000^(-i/32)
    float ang = (float)s * inv;
    float sn, cs;
    sincosf(ang, &sn, &cs);
    p[i] = f2b(t1 * cs - t2 * sn);
    p[i + 32] = f2b(t2 * cs + t1 * sn);
}

// ---------------- causal flash attention: 4 waves x 32 q-rows, swapped-QK 32x32 ----------------
// Double-buffered K/V LDS; one barrier per tile; all staging via global_load_lds.
__global__ __launch_bounds__(256, 2) void attn_kernel(
    const short* __restrict__ Q, const short* __restrict__ Kg,
    const short* __restrict__ Vt, short* __restrict__ ctx) {
    __shared__ short Ksm[2][64 * 192];    // 2 x 24KB, swizzled linear
    __shared__ short Vsm[2][128 * 64];    // 2 x 16KB, V^T (d,k), swizzled
    int tid = threadIdx.x, lane = tid & 63, w = tid >> 6;
    int hf = lane >> 5, l31 = lane & 31;
    // complementary-pair mapping (blocks c and c+256 share a CU)
    int bid = blockIdx.x;
    int half = bid >> 8, a = (bid & 255) >> 5;
    int qt = half ? a : 15 - a;
    int bh = bid & 31;
    int bb = bh >> 4, hd = bh & 15;
    int q0 = qt * 128;
    const short* Qp = Q + (size_t)bh * SS * DQK;
    const short* Kp = Kg + (size_t)bh * SS * DQK;
    const char*  Vp = (const char*)(Vt + (size_t)bh * HDD * SS);
    int wr0 = q0 + w * 32;
    int qrow = wr0 + l31;               // this lane's softmax row
    const float scale = 0.07216878364870323f;   // 1/sqrt(192)
    const float L2E = 1.44269504088896f;

    // Q as B-operand fragments: B[k=8*hf+j][col=l31], dims 16s+8hf+j
    bf16x8 qf[12];
#pragma unroll
    for (int s = 0; s < 12; s++)
        qf[s] = *(const bf16x8*)(Qp + (size_t)qrow * DQK + s * 16 + hf * 8);

    f32x16 acc[4] = {};   // O: acc[n] rows=(r&3)+8*(r>>2)+4*hf, d=n*32+l31
    float mrow = -1e30f, lsum = 0.f;
    int nt = 2 * qt + 2;

    auto stageK = [&](int key0, int b) {
#pragma unroll
        for (int pp = 0; pp < 6; pp++) {
            int flat = pp * 4096 + tid * 16;          // byte offset in 64x384B tile
            int row = flat / 384, bir = flat - row * 384;
            const char* src = (const char*)Kp + (size_t)(key0 + row) * 384 + (bir ^ ((row & 7) << 4));
            GLOAD16(src, (char*)Ksm[b] + flat);
        }
    };
    auto stageV = [&](int key0, int b) {
#pragma unroll
        for (int c = 0; c < 4; c++) {
            int flat = c * 4096 + tid * 16;           // byte offset in 128x128B tile
            int d = flat >> 7, bik = flat & 127;
            const char* src = Vp + (size_t)d * (SS * 2) + (size_t)key0 * 2 + (bik ^ ((d & 7) << 4));
            GLOAD16(src, (char*)Vsm[b] + flat);
        }
    };

    stageK(0, 0); stageV(0, 0);
    __syncthreads();   // tile 0 ready

    for (int t0 = 0; t0 < nt; t0++) {
        int key0 = t0 * 64;
        int cur = t0 & 1;
        if (t0 + 1 < nt) { stageK(key0 + 64, cur ^ 1); stageV(key0 + 64, cur ^ 1); }
        bool active = (key0 <= wr0 + 31);
        if (active) {
            // ---- swapped QK^T: D[key][qrow] ----
            f32x16 z = {};
            f32x16 sv0 = z, sv1 = z;
            int xr = (l31 & 7) << 4;
            const char* Kb = (const char*)Ksm[cur];
            __builtin_amdgcn_s_setprio(1);
#pragma unroll
            for (int s = 0; s < 12; s++) {
                bf16x8 k0 = *(const bf16x8*)(Kb + l31 * 384 + ((s * 32 + hf * 16) ^ xr));
                bf16x8 k1 = *(const bf16x8*)(Kb + (32 + l31) * 384 + ((s * 32 + hf * 16) ^ xr));
                sv0 = __builtin_amdgcn_mfma_f32_32x32x16_bf16(k0, qf[s], sv0, 0, 0, 0);
                sv1 = __builtin_amdgcn_mfma_f32_32x32x16_bf16(k1, qf[s], sv1, 0, 0, 0);
            }
            __builtin_amdgcn_s_setprio(0);
            // ---- mask (raw scores; scale folded into exp) ----
            bool domask = (key0 + 63 > wr0);
            float p[32];
#pragma unroll
            for (int t = 0; t < 2; t++)
#pragma unroll
                for (int r = 0; r < 16; r++) {
                    float v = (t ? sv1[r] : sv0[r]);
                    int key = key0 + 32 * t + (r & 3) + 8 * (r >> 2) + 4 * hf;
                    if (domask && key > qrow) v = -1e30f;
                    p[t * 16 + r] = v;
                }
            // ---- tree max (5-deep instead of 31-deep serial chain) ----
            float tm[16];
#pragma unroll
            for (int i = 0; i < 16; i++) tm[i] = fmaxf(p[i], p[i + 16]);
#pragma unroll
            for (int i = 0; i < 8; i++) tm[i] = fmaxf(tm[i], tm[i + 8]);
#pragma unroll
            for (int i = 0; i < 4; i++) tm[i] = fmaxf(tm[i], tm[i + 4]);
            float pmaxs = fmaxf(fmaxf(tm[0], tm[1]), fmaxf(tm[2], tm[3])) * scale;
            // ---- defer-max rescale (common max computed only when needed) ----
            if (__any(pmaxs > mrow + 8.f)) {
                float pc = fmaxf(pmaxs, __shfl_xor(pmaxs, 32, 64));
                float mn = fmaxf(mrow, pc);
                float al = exp2f((mrow - mn) * L2E);
                mrow = mn;
                lsum *= al;
                float arl[16];
#pragma unroll
                for (int r = 0; r < 16; r++)
                    arl[r] = __shfl(al, (r & 3) + 8 * (r >> 2) + 4 * hf, 64);
#pragma unroll
                for (int n = 0; n < 4; n++)
#pragma unroll
                    for (int r = 0; r < 16; r++)
                        acc[n][r] *= arl[r];
            }
            // ---- exp with folded scale: exp2(p*scale*L2E - mrow*L2E) ----
            float sL = scale * L2E, mL = mrow * L2E;
#pragma unroll
            for (int i = 0; i < 32; i++)
                p[i] = exp2f(fmaf(p[i], sL, -mL));
            // ---- tree sum ----
            float ts[16];
#pragma unroll
            for (int i = 0; i < 16; i++) ts[i] = p[i] + p[i + 16];
#pragma unroll
            for (int i = 0; i < 8; i++) ts[i] = ts[i] + ts[i + 8];
#pragma unroll
            for (int i = 0; i < 4; i++) ts[i] = ts[i] + ts[i + 4];
            lsum += (ts[0] + ts[1]) + (ts[2] + ts[3]);
            // ---- pack P to bf16 + exchange halves for ALL slices first ----
            bf16x8 afv[4];
#pragma unroll
            for (int g = 0; g < 4; g++) {   // slice g: keys key0+16g..+15
                int base = (g >> 1) * 16 + (g & 1) * 8;
                unsigned a01 = cvtpk(p[base + 0], p[base + 1]);
                unsigned a23 = cvtpk(p[base + 2], p[base + 3]);
                unsigned b01 = cvtpk(p[base + 4], p[base + 5]);
                unsigned b23 = cvtpk(p[base + 6], p[base + 7]);
                unsigned s0 = hf ? a01 : b01, s1 = hf ? a23 : b23;
                unsigned r0 = (unsigned)__shfl_xor((int)s0, 32, 64);
                unsigned r1 = (unsigned)__shfl_xor((int)s1, 32, 64);
                union { unsigned u[4]; bf16x8 v; } af;
                af.u[0] = hf ? r0 : a01;
                af.u[1] = hf ? r1 : a23;
                af.u[2] = hf ? b01 : r0;
                af.u[3] = hf ? b23 : r1;
                afv[g] = af.v;
            }
            // ---- PV ----
            const char* Vb = (const char*)Vsm[cur];
            __builtin_amdgcn_s_setprio(1);
#pragma unroll
            for (int g = 0; g < 4; g++)
#pragma unroll
                for (int n = 0; n < 4; n++) {
                    int d = n * 32 + l31;
                    bf16x8 vf = *(const bf16x8*)(Vb + d * 128 + ((g * 32 + hf * 16) ^ ((d & 7) << 4)));
                    acc[n] = __builtin_amdgcn_mfma_f32_32x32x16_bf16(afv[g], vf, acc[n], 0, 0, 0);
                }
            __builtin_amdgcn_s_setprio(0);
        }
        // one barrier per tile: syncs all waves' reads of buf[cur] and drains
        // this tile's prefetch (issued a full tile ago -> no stall)
        __syncthreads();
    }
    // ---- epilogue ----
    lsum += __shfl_xor(lsum, 32, 64);
    float rc = 1.0f / lsum;
    float rcl[16];
#pragma unroll
    for (int r = 0; r < 16; r++)
        rcl[r] = __shfl(rc, (r & 3) + 8 * (r >> 2) + 4 * hf, 64);
#pragma unroll
    for (int n = 0; n < 4; n++)
#pragma unroll
        for (int r = 0; r < 16; r++) {
            int row = wr0 + (r & 3) + 8 * (r >> 2) + 4 * hf;
            int d = n * 32 + l31;
            ctx[((size_t)(bb * SS + row)) * (NHH * HDD) + hd * HDD + d] = f2b(acc[n][r] * rcl[r]);
        }
}

extern "C" void kernel_launch(void* const* d_in, const int* in_sizes, int n_in,
                              void* d_out, int out_size, void* d_ws, size_t ws_size,
                              hipStream_t stream) {
    const float* x     = (const float*)d_in[0];
    const float* W_kvd = (const float*)d_in[1];  const float* b_kvd = (const float*)d_in[2];
    const float* W_ku  = (const float*)d_in[3];  const float* b_ku  = (const float*)d_in[4];
    const float* W_vu  = (const float*)d_in[5];  const float* b_vu  = (const float*)d_in[6];
    const float* W_kr  = (const float*)d_in[7];  const float* b_kr  = (const float*)d_in[8];
    const float* W_qd  = (const float*)d_in[9];  const float* b_qd  = (const float*)d_in[10];
    const float* W_qu  = (const float*)d_in[11]; const float* b_qu  = (const float*)d_in[12];
    const float* W_qr  = (const float*)d_in[13]; const float* b_qr  = (const float*)d_in[14];
    const float* W_o   = (const float*)d_in[15]; const float* b_o   = (const float*)d_in[16];
    float* out = (float*)d_out;

    char* p = (char*)d_ws;
    auto alloc = [&](size_t elems) {
        short* r = (short*)p;
        p += ((elems * 2) + 255) & ~(size_t)255;
        return r;
    };
    short* xb   = alloc((size_t)MROWS * HIDD);
    short* kvc  = alloc((size_t)MROWS * KVCC);
    short* qc   = alloc((size_t)MROWS * QCC);
    short* kbuf = alloc((size_t)BB * NHH * SS * DQK);
    short* qbuf = alloc((size_t)BB * NHH * SS * DQK);
    short* vtb  = alloc((size_t)BB * NHH * HDD * SS);
    short* ctx  = alloc((size_t)MROWS * NHH * HDD);
    short* Wt1  = alloc((size_t)2048 * 2048);
    short* Wt2  = alloc((size_t)5120 * 512);
    short* Wt3  = alloc((size_t)3072 * 1536);
    short* Wt4  = alloc((size_t)2048 * 2048);

    cvt_kernel<<<dim3((MROWS * HIDD) / 1024), dim3(256), 0, stream>>>(x, xb);
    dim3 tb(32, 8);
    wtrans_kernel<<<dim3(15360), tb, 0, stream>>>(
        W_kvd, W_qd, W_ku, W_vu, W_kr, W_qu, W_qr, W_o, Wt1, Wt2, Wt3, Wt4);

    gemm128<1><<<dim3(2048 / 128, MROWS / 128), 256, 0, stream>>>(
        xb, Wt1, b_kvd, b_qd, nullptr, kvc, qc, MROWS, 2048, 2048);
    gemm128<2><<<dim3(5120 / 128, MROWS / 128), 256, 0, stream>>>(
        kvc, Wt2, b_ku, b_vu, b_kr, kbuf, vtb, MROWS, 5120, 512);
    gemm128<3><<<dim3(3072 / 128, MROWS / 128), 256, 0, stream>>>(
        qc, Wt3, b_qu, b_qr, nullptr, qbuf, nullptr, MROWS, 3072, 1536);

    rope_kernel<<<dim3((2 * BB * NHH * SS * 32) / 256), dim3(256), 0, stream>>>(kbuf, qbuf);

    attn_kernel<<<dim3(512), 256, 0, stream>>>(qbuf, kbuf, vtb, ctx);

    gemm128<0><<<dim3(HIDD / 128, MROWS / 128), 256, 0, stream>>>(
        ctx, Wt4, b_o, nullptr, nullptr, out, nullptr, MROWS, HIDD, NHH * HDD);
}

// Round 15
// 387.761 us; speedup vs baseline: 1.1594x; 1.0180x over previous
//
#include <hip/hip_runtime.h>
#include <math.h>

#define BB   2
#define SS   2048
#define HIDD 2048
#define NHH  16
#define HDD  128
#define RDD  64
#define KVCC 512
#define QCC  1536
#define DQK  192
#define MROWS 4096

using bf16x8 = __attribute__((ext_vector_type(8))) short;
using short4v = __attribute__((ext_vector_type(4))) short;
using f32x4  = __attribute__((ext_vector_type(4))) float;
using f32x16 = __attribute__((ext_vector_type(16))) float;

static __device__ __forceinline__ float b2f(short s) {
    unsigned u = ((unsigned)(unsigned short)s) << 16;
    union { unsigned u; float f; } v; v.u = u; return v.f;
}
static __device__ __forceinline__ short f2b(float f) {
    union { float f; unsigned u; } v; v.f = f;
    unsigned r = (v.u + 0x7fffu + ((v.u >> 16) & 1u)) >> 16;
    return (short)r;
}
static __device__ __forceinline__ unsigned cvtpk(float lo, float hi) {
    unsigned r;
    asm("v_cvt_pk_bf16_f32 %0, %1, %2" : "=v"(r) : "v"(lo), "v"(hi));
    return r;
}

#define GLOAD16(gsrc, ldst) \
    __builtin_amdgcn_global_load_lds((const __attribute__((address_space(1))) void*)(gsrc), \
                                     (__attribute__((address_space(3))) void*)(ldst), 16, 0, 0)

// ---------------- fp32 -> bf16 convert ----------------
__global__ void cvt_kernel(const float* __restrict__ in, short* __restrict__ out) {
    int i = (blockIdx.x * blockDim.x + threadIdx.x) * 4;
    float4 v = *(const float4*)(in + i);
    short4v o;
    o[0] = f2b(v.x); o[1] = f2b(v.y); o[2] = f2b(v.z); o[3] = f2b(v.w);
    *(short4v*)(out + i) = o;
}

// ---------------- all 8 weight transposes in ONE launch ----------------
__global__ void wtrans_kernel(
    const float* __restrict__ W0, const float* __restrict__ W1,
    const float* __restrict__ W2, const float* __restrict__ W3,
    const float* __restrict__ W4, const float* __restrict__ W5,
    const float* __restrict__ W6, const float* __restrict__ W7,
    short* __restrict__ D0, short* __restrict__ D1,
    short* __restrict__ D2, short* __restrict__ D3) {
    __shared__ float t[32][33];
    int bid = blockIdx.x;
    const float* W; short* Dst; int K, N, lt;
    if (bid < 4096) {
        if (bid < 1024) { W = W0; Dst = D0;                        K = 2048; N = 512;  lt = bid; }
        else            { W = W1; Dst = D0 + (size_t)512 * 2048;   K = 2048; N = 1536; lt = bid - 1024; }
    } else if (bid < 6656) {
        if (bid < 5120)      { W = W2; Dst = D1;                       K = 512; N = 2048; lt = bid - 4096; }
        else if (bid < 6144) { W = W3; Dst = D1 + (size_t)2048 * 512;  K = 512; N = 2048; lt = bid - 5120; }
        else                 { W = W4; Dst = D1 + (size_t)4096 * 512;  K = 512; N = 1024; lt = bid - 6144; }
    } else if (bid < 11264) {
        if (bid < 9728) { W = W5; Dst = D2;                        K = 1536; N = 2048; lt = bid - 6656; }
        else            { W = W6; Dst = D2 + (size_t)2048 * 1536;  K = 1536; N = 1024; lt = bid - 9728; }
    } else { W = W7; Dst = D3; K = 2048; N = 2048; lt = bid - 11264; }
    int ntx = N >> 5;
    int n0 = (lt % ntx) * 32, k0 = (lt / ntx) * 32;
    int tx = threadIdx.x, ty = threadIdx.y;   // block(32,8)
#pragma unroll
    for (int i = 0; i < 4; i++)
        t[ty + i * 8][tx] = W[(size_t)(k0 + ty + i * 8) * N + n0 + tx];
    __syncthreads();
#pragma unroll
    for (int i = 0; i < 4; i++)
        Dst[(size_t)(n0 + ty + i * 8) * K + k0 + tx] = f2b(t[tx][ty + i * 8]);
}

// ---------------- 128x128 MFMA GEMM, 3-buffer counted-vmcnt pipeline (T4) ----------
// Loads stay in flight across raw s_barriers; wait is vmcnt(4), never 0 (except last).
// ID 0: fp32 out (+b0).  ID 1: [kvc|qc] bf16.
// ID 2: [ku->kbuf | vu->vtb TRANSPOSED (bh,d,s) | kr->kbuf].  ID 3: [qu|qr]->qbuf.
template <int ID>
__global__ __launch_bounds__(256) void gemm128(
    const short* __restrict__ A, const short* __restrict__ Bt,
    const float* __restrict__ b0, const float* __restrict__ b1, const float* __restrict__ b2,
    void* __restrict__ C0, void* __restrict__ C1,
    int M, int N, int K) {
    __shared__ short Asm[3][4096];   // 3 x [128][32]
    __shared__ short Bsm[3][4096];
    int tid = threadIdx.x, lane = tid & 63, w = tid >> 6;
    int wm = w >> 1, wn = w & 1;
    int m0 = blockIdx.y * 128, n0 = blockIdx.x * 128;
    int fr = lane & 15, fk = (lane >> 4) * 8;
    const short* Ag = A + (size_t)(m0 + (tid >> 2)) * K + (tid & 3) * 8;
    const short* Bg = Bt + (size_t)(n0 + (tid >> 2)) * K + (tid & 3) * 8;
    auto stage = [&](int t, int b) {
        int k0 = t * 32;
        GLOAD16(Ag + k0, &Asm[b][tid * 8]);
        GLOAD16(Ag + k0 + (size_t)64 * K, &Asm[b][2048 + tid * 8]);
        GLOAD16(Bg + k0, &Bsm[b][tid * 8]);
        GLOAD16(Bg + k0 + (size_t)64 * K, &Bsm[b][2048 + tid * 8]);
    };
    f32x4 acc[4][4] = {};
    int NT = K >> 5;
    stage(0, 0);
    stage(1, 1);
    for (int t = 0; t < NT; t++) {
        int cur = t % 3;
        // own tile-t loads retired (tile t+1 / t+2 may stay in flight):
        if (t + 1 < NT) asm volatile("s_waitcnt vmcnt(4)" ::: "memory");
        else            asm volatile("s_waitcnt vmcnt(0)" ::: "memory");
        __builtin_amdgcn_s_barrier();   // all waves' tile-t loads visible
        bf16x8 af[4], bfv[4];
#pragma unroll
        for (int m = 0; m < 4; m++)
            af[m] = *(const bf16x8*)&Asm[cur][(wm * 64 + m * 16 + fr) * 32 + fk];
#pragma unroll
        for (int n = 0; n < 4; n++)
            bfv[n] = *(const bf16x8*)&Bsm[cur][(wn * 64 + n * 16 + fr) * 32 + fk];
#pragma unroll
        for (int m = 0; m < 4; m++)
#pragma unroll
            for (int n = 0; n < 4; n++)
                acc[m][n] = __builtin_amdgcn_mfma_f32_16x16x32_bf16(af[m], bfv[n], acc[m][n], 0, 0, 0);
        __builtin_amdgcn_s_barrier();   // all waves done reading buf[cur]
        if (t + 2 < NT) stage(t + 2, (t + 2) % 3);   // overwrites buf[(t-1)%3]: safe
    }
#pragma unroll
    for (int m = 0; m < 4; m++)
#pragma unroll
        for (int n = 0; n < 4; n++)
#pragma unroll
            for (int r = 0; r < 4; r++) {
                int row = m0 + wm * 64 + m * 16 + ((lane >> 4) << 2) + r;
                int col = n0 + wn * 64 + n * 16 + fr;
                float v = acc[m][n][r];
                if constexpr (ID == 0) {
                    ((float*)C0)[(size_t)row * N + col] = v + b0[col];
                } else if constexpr (ID == 1) {
                    if (col < KVCC)
                        ((short*)C0)[(size_t)row * KVCC + col] = f2b(v + b0[col]);
                    else
                        ((short*)C1)[(size_t)row * QCC + (col - KVCC)] = f2b(v + b1[col - KVCC]);
                } else if constexpr (ID == 2) {
                    int b = row >> 11, s = row & (SS - 1);
                    if (col < 2048) {
                        int h = col >> 7, d = col & 127;
                        ((short*)C0)[(((size_t)(b * NHH + h)) * SS + s) * DQK + d] = f2b(v + b0[col]);
                    } else if (col < 4096) {
                        int c = col - 2048; int h = c >> 7, d = c & 127;
                        // direct transposed (bh, d, s) for attention V
                        ((short*)C1)[(((size_t)(b * NHH + h)) * HDD + d) * SS + s] = f2b(v + b1[c]);
                    } else {
                        int c = col - 4096; int h = c >> 6, d = c & 63;
                        ((short*)C0)[(((size_t)(b * NHH + h)) * SS + s) * DQK + HDD + d] = f2b(v + b2[c]);
                    }
                } else {
                    int b = row >> 11, s = row & (SS - 1);
                    if (col < 2048) {
                        int h = col >> 7, d = col & 127;
                        ((short*)C0)[(((size_t)(b * NHH + h)) * SS + s) * DQK + d] = f2b(v + b0[col]);
                    } else {
                        int c = col - 2048; int h = c >> 6, d = c & 63;
                        ((short*)C0)[(((size_t)(b * NHH + h)) * SS + s) * DQK + HDD + d] = f2b(v + b1[c]);
                    }
                }
            }
}

// ---------------- RoPE on [*, *, 128..191] of (B*NH, S, 192), both K and Q ----------------
__global__ void rope_kernel(short* __restrict__ Tk, short* __restrict__ Tq) {
    int idx = blockIdx.x * blockDim.x + threadIdx.x;
    const int HALF = BB * NHH * SS * 32;
    short* T = (idx < HALF) ? Tk : Tq;
    int id = (idx < HALF) ? idx : idx - HALF;
    int i = id & 31;
    int s = (id >> 5) & (SS - 1);
    int bh = id >> 16;
    short* p = T + ((size_t)bh * SS + s) * DQK + HDD;
    float t1 = b2f(p[i]), t2 = b2f(p[i + 32]);
    float inv = exp2f(-(float)i * 0.41524101186092034f);   // 10000^(-i/32)
    float ang = (float)s * inv;
    float sn, cs;
    sincosf(ang, &sn, &cs);
    p[i] = f2b(t1 * cs - t2 * sn);
    p[i + 32] = f2b(t2 * cs + t1 * sn);
}

// ---------------- causal flash attention: 4 waves x 32 q-rows, swapped-QK 32x32 ----------------
// Double-buffered K/V LDS; one barrier per tile; all staging via global_load_lds.
__global__ __launch_bounds__(256, 2) void attn_kernel(
    const short* __restrict__ Q, const short* __restrict__ Kg,
    const short* __restrict__ Vt, short* __restrict__ ctx) {
    __shared__ short Ksm[2][64 * 192];    // 2 x 24KB, swizzled linear
    __shared__ short Vsm[2][128 * 64];    // 2 x 16KB, V^T (d,k), swizzled
    int tid = threadIdx.x, lane = tid & 63, w = tid >> 6;
    int hf = lane >> 5, l31 = lane & 31;
    // complementary-pair mapping (blocks c and c+256 share a CU)
    int bid = blockIdx.x;
    int half = bid >> 8, a = (bid & 255) >> 5;
    int qt = half ? a : 15 - a;
    int bh = bid & 31;
    int bb = bh >> 4, hd = bh & 15;
    int q0 = qt * 128;
    const short* Qp = Q + (size_t)bh * SS * DQK;
    const short* Kp = Kg + (size_t)bh * SS * DQK;
    const char*  Vp = (const char*)(Vt + (size_t)bh * HDD * SS);
    int wr0 = q0 + w * 32;
    int qrow = wr0 + l31;               // this lane's softmax row
    const float scale = 0.07216878364870323f;   // 1/sqrt(192)
    const float L2E = 1.44269504088896f;

    // Q as B-operand fragments: B[k=8*hf+j][col=l31], dims 16s+8hf+j
    bf16x8 qf[12];
#pragma unroll
    for (int s = 0; s < 12; s++)
        qf[s] = *(const bf16x8*)(Qp + (size_t)qrow * DQK + s * 16 + hf * 8);

    f32x16 acc[4] = {};   // O: acc[n] rows=(r&3)+8*(r>>2)+4*hf, d=n*32+l31
    float mrow = -1e30f, lsum = 0.f;
    int nt = 2 * qt + 2;

    auto stageK = [&](int key0, int b) {
#pragma unroll
        for (int pp = 0; pp < 6; pp++) {
            int flat = pp * 4096 + tid * 16;          // byte offset in 64x384B tile
            int row = flat / 384, bir = flat - row * 384;
            const char* src = (const char*)Kp + (size_t)(key0 + row) * 384 + (bir ^ ((row & 7) << 4));
            GLOAD16(src, (char*)Ksm[b] + flat);
        }
    };
    auto stageV = [&](int key0, int b) {
#pragma unroll
        for (int c = 0; c < 4; c++) {
            int flat = c * 4096 + tid * 16;           // byte offset in 128x128B tile
            int d = flat >> 7, bik = flat & 127;
            const char* src = Vp + (size_t)d * (SS * 2) + (size_t)key0 * 2 + (bik ^ ((d & 7) << 4));
            GLOAD16(src, (char*)Vsm[b] + flat);
        }
    };

    stageK(0, 0); stageV(0, 0);
    __syncthreads();   // tile 0 ready

    for (int t0 = 0; t0 < nt; t0++) {
        int key0 = t0 * 64;
        int cur = t0 & 1;
        if (t0 + 1 < nt) { stageK(key0 + 64, cur ^ 1); stageV(key0 + 64, cur ^ 1); }
        bool active = (key0 <= wr0 + 31);
        if (active) {
            // ---- swapped QK^T: D[key][qrow] ----
            f32x16 z = {};
            f32x16 sv0 = z, sv1 = z;
            int xr = (l31 & 7) << 4;
            const char* Kb = (const char*)Ksm[cur];
            __builtin_amdgcn_s_setprio(1);
#pragma unroll
            for (int s = 0; s < 12; s++) {
                bf16x8 k0 = *(const bf16x8*)(Kb + l31 * 384 + ((s * 32 + hf * 16) ^ xr));
                bf16x8 k1 = *(const bf16x8*)(Kb + (32 + l31) * 384 + ((s * 32 + hf * 16) ^ xr));
                sv0 = __builtin_amdgcn_mfma_f32_32x32x16_bf16(k0, qf[s], sv0, 0, 0, 0);
                sv1 = __builtin_amdgcn_mfma_f32_32x32x16_bf16(k1, qf[s], sv1, 0, 0, 0);
            }
            __builtin_amdgcn_s_setprio(0);
            // ---- mask (raw scores; scale folded into exp) ----
            bool domask = (key0 + 63 > wr0);
            float p[32];
#pragma unroll
            for (int t = 0; t < 2; t++)
#pragma unroll
                for (int r = 0; r < 16; r++) {
                    float v = (t ? sv1[r] : sv0[r]);
                    int key = key0 + 32 * t + (r & 3) + 8 * (r >> 2) + 4 * hf;
                    if (domask && key > qrow) v = -1e30f;
                    p[t * 16 + r] = v;
                }
            // ---- tree max (5-deep instead of 31-deep serial chain) ----
            float tm[16];
#pragma unroll
            for (int i = 0; i < 16; i++) tm[i] = fmaxf(p[i], p[i + 16]);
#pragma unroll
            for (int i = 0; i < 8; i++) tm[i] = fmaxf(tm[i], tm[i + 8]);
#pragma unroll
            for (int i = 0; i < 4; i++) tm[i] = fmaxf(tm[i], tm[i + 4]);
            float pmaxs = fmaxf(fmaxf(tm[0], tm[1]), fmaxf(tm[2], tm[3])) * scale;
            // ---- defer-max rescale (common max computed only when needed) ----
            if (__any(pmaxs > mrow + 8.f)) {
                float pc = fmaxf(pmaxs, __shfl_xor(pmaxs, 32, 64));
                float mn = fmaxf(mrow, pc);
                float al = exp2f((mrow - mn) * L2E);
                mrow = mn;
                lsum *= al;
                float arl[16];
#pragma unroll
                for (int r = 0; r < 16; r++)
                    arl[r] = __shfl(al, (r & 3) + 8 * (r >> 2) + 4 * hf, 64);
#pragma unroll
                for (int n = 0; n < 4; n++)
#pragma unroll
                    for (int r = 0; r < 16; r++)
                        acc[n][r] *= arl[r];
            }
            // ---- exp with folded scale: exp2(p*scale*L2E - mrow*L2E) ----
            float sL = scale * L2E, mL = mrow * L2E;
#pragma unroll
            for (int i = 0; i < 32; i++)
                p[i] = exp2f(fmaf(p[i], sL, -mL));
            // ---- tree sum ----
            float ts[16];
#pragma unroll
            for (int i = 0; i < 16; i++) ts[i] = p[i] + p[i + 16];
#pragma unroll
            for (int i = 0; i < 8; i++) ts[i] = ts[i] + ts[i + 8];
#pragma unroll
            for (int i = 0; i < 4; i++) ts[i] = ts[i] + ts[i + 4];
            lsum += (ts[0] + ts[1]) + (ts[2] + ts[3]);
            // ---- pack P to bf16 + exchange halves for ALL slices first ----
            bf16x8 afv[4];
#pragma unroll
            for (int g = 0; g < 4; g++) {   // slice g: keys key0+16g..+15
                int base = (g >> 1) * 16 + (g & 1) * 8;
                unsigned a01 = cvtpk(p[base + 0], p[base + 1]);
                unsigned a23 = cvtpk(p[base + 2], p[base + 3]);
                unsigned b01 = cvtpk(p[base + 4], p[base + 5]);
                unsigned b23 = cvtpk(p[base + 6], p[base + 7]);
                unsigned s0 = hf ? a01 : b01, s1 = hf ? a23 : b23;
                unsigned r0 = (unsigned)__shfl_xor((int)s0, 32, 64);
                unsigned r1 = (unsigned)__shfl_xor((int)s1, 32, 64);
                union { unsigned u[4]; bf16x8 v; } af;
                af.u[0] = hf ? r0 : a01;
                af.u[1] = hf ? r1 : a23;
                af.u[2] = hf ? b01 : r0;
                af.u[3] = hf ? b23 : r1;
                afv[g] = af.v;
            }
            // ---- PV ----
            const char* Vb = (const char*)Vsm[cur];
            __builtin_amdgcn_s_setprio(1);
#pragma unroll
            for (int g = 0; g < 4; g++)
#pragma unroll
                for (int n = 0; n < 4; n++) {
                    int d = n * 32 + l31;
                    bf16x8 vf = *(const bf16x8*)(Vb + d * 128 + ((g * 32 + hf * 16) ^ ((d & 7) << 4)));
                    acc[n] = __builtin_amdgcn_mfma_f32_32x32x16_bf16(afv[g], vf, acc[n], 0, 0, 0);
                }
            __builtin_amdgcn_s_setprio(0);
        }
        // one barrier per tile: syncs all waves' reads of buf[cur] and drains
        // this tile's prefetch (issued a full tile ago -> no stall)
        __syncthreads();
    }
    // ---- epilogue ----
    lsum += __shfl_xor(lsum, 32, 64);
    float rc = 1.0f / lsum;
    float rcl[16];
#pragma unroll
    for (int r = 0; r < 16; r++)
        rcl[r] = __shfl(rc, (r & 3) + 8 * (r >> 2) + 4 * hf, 64);
#pragma unroll
    for (int n = 0; n < 4; n++)
#pragma unroll
        for (int r = 0; r < 16; r++) {
            int row = wr0 + (r & 3) + 8 * (r >> 2) + 4 * hf;
            int d = n * 32 + l31;
            ctx[((size_t)(bb * SS + row)) * (NHH * HDD) + hd * HDD + d] = f2b(acc[n][r] * rcl[r]);
        }
}

extern "C" void kernel_launch(void* const* d_in, const int* in_sizes, int n_in,
                              void* d_out, int out_size, void* d_ws, size_t ws_size,
                              hipStream_t stream) {
    const float* x     = (const float*)d_in[0];
    const float* W_kvd = (const float*)d_in[1];  const float* b_kvd = (const float*)d_in[2];
    const float* W_ku  = (const float*)d_in[3];  const float* b_ku  = (const float*)d_in[4];
    const float* W_vu  = (const float*)d_in[5];  const float* b_vu  = (const float*)d_in[6];
    const float* W_kr  = (const float*)d_in[7];  const float* b_kr  = (const float*)d_in[8];
    const float* W_qd  = (const float*)d_in[9];  const float* b_qd  = (const float*)d_in[10];
    const float* W_qu  = (const float*)d_in[11]; const float* b_qu  = (const float*)d_in[12];
    const float* W_qr  = (const float*)d_in[13]; const float* b_qr  = (const float*)d_in[14];
    const float* W_o   = (const float*)d_in[15]; const float* b_o   = (const float*)d_in[16];
    float* out = (float*)d_out;

    char* p = (char*)d_ws;
    auto alloc = [&](size_t elems) {
        short* r = (short*)p;
        p += ((elems * 2) + 255) & ~(size_t)255;
        return r;
    };
    short* xb   = alloc((size_t)MROWS * HIDD);
    short* kvc  = alloc((size_t)MROWS * KVCC);
    short* qc   = alloc((size_t)MROWS * QCC);
    short* kbuf = alloc((size_t)BB * NHH * SS * DQK);
    short* qbuf = alloc((size_t)BB * NHH * SS * DQK);
    short* vtb  = alloc((size_t)BB * NHH * HDD * SS);
    short* ctx  = alloc((size_t)MROWS * NHH * HDD);
    short* Wt1  = alloc((size_t)2048 * 2048);
    short* Wt2  = alloc((size_t)5120 * 512);
    short* Wt3  = alloc((size_t)3072 * 1536);
    short* Wt4  = alloc((size_t)2048 * 2048);

    cvt_kernel<<<dim3((MROWS * HIDD) / 1024), dim3(256), 0, stream>>>(x, xb);
    dim3 tb(32, 8);
    wtrans_kernel<<<dim3(15360), tb, 0, stream>>>(
        W_kvd, W_qd, W_ku, W_vu, W_kr, W_qu, W_qr, W_o, Wt1, Wt2, Wt3, Wt4);

    gemm128<1><<<dim3(2048 / 128, MROWS / 128), 256, 0, stream>>>(
        xb, Wt1, b_kvd, b_qd, nullptr, kvc, qc, MROWS, 2048, 2048);
    gemm128<2><<<dim3(5120 / 128, MROWS / 128), 256, 0, stream>>>(
        kvc, Wt2, b_ku, b_vu, b_kr, kbuf, vtb, MROWS, 5120, 512);
    gemm128<3><<<dim3(3072 / 128, MROWS / 128), 256, 0, stream>>>(
        qc, Wt3, b_qu, b_qr, nullptr, qbuf, nullptr, MROWS, 3072, 1536);

    rope_kernel<<<dim3((2 * BB * NHH * SS * 32) / 256), dim3(256), 0, stream>>>(kbuf, qbuf);

    attn_kernel<<<dim3(512), 256, 0, stream>>>(qbuf, kbuf, vtb, ctx);

    gemm128<0><<<dim3(HIDD / 128, MROWS / 128), 256, 0, stream>>>(
        ctx, Wt4, b_o, nullptr, nullptr, out, nullptr, MROWS, HIDD, NHH * HDD);
}